// Round 1
// baseline (633.085 us; speedup 1.0000x reference)
//
#include <hip/hip_runtime.h>
#include <hip/hip_bf16.h>

#define NB 16
#define NA 1614

// ---------------- conv1: rpn_feature [16,2048,14,14] * w[128,2048,3,3] pad1 ----------------
// split-K: grid 512 = 8 k-chunks x 4 oc-tiles x 16 batches. Each block: 32 oc x 196 pos, K=256 ic.
__global__ __launch_bounds__(256, 2)
void conv1_part(const float* __restrict__ in, const float* __restrict__ w,
                float* __restrict__ part) {
  const int bid = blockIdx.x;
  const int kc  = bid & 7;
  const int oct = (bid >> 3) & 3;
  const int b   = bid >> 5;
  const int ic0 = kc * 256;
  const int oc0 = oct * 32;
  const int tid = threadIdx.x;
  const int ocg  = tid >> 5;   // 0..7 -> oc = oc0 + ocg*4 + i
  const int posg = tid & 31;   // positions posg + 32*j, j=0..6

  __shared__ float s_in[8 * 256];    // 8 ch x (16x16 padded tile)
  __shared__ float s_w[32 * 72];     // 32 oc x (8 ic x 9)

  float acc[4][7];
#pragma unroll
  for (int i = 0; i < 4; i++)
#pragma unroll
    for (int j = 0; j < 7; j++) acc[i][j] = 0.f;

  int pofs[7];
  bool pval[7];
#pragma unroll
  for (int j = 0; j < 7; j++) {
    int p = posg + 32 * j;
    pval[j] = (p < 196);
    int y = pval[j] ? (p / 14) : 0;
    int x = pval[j] ? (p % 14) : 0;
    pofs[j] = y * 16 + x;   // + ky*16 + kx gives padded-tile address
  }

  const float* inb = in + (size_t)b * 2048 * 196;

  for (int icb = 0; icb < 256; icb += 8) {
    __syncthreads();
    // stage input: 8 channels, 16x16 padded
#pragma unroll
    for (int r = 0; r < 8; r++) {
      int e = tid + 256 * r;
      int ch = e >> 8, idx = e & 255;
      int ty = idx >> 4, tx = idx & 15;
      int iy = ty - 1, ix = tx - 1;
      float v = 0.f;
      if ((unsigned)iy < 14u && (unsigned)ix < 14u)
        v = inb[(size_t)(ic0 + icb + ch) * 196 + iy * 14 + ix];
      s_in[e] = v;
    }
    // stage weights: 32 oc x 8 ic x 9 (contiguous 72-float chunks per oc)
#pragma unroll
    for (int r = 0; r < 9; r++) {
      int e = tid + 256 * r;   // 0..2303
      int oce = e / 72;
      int rem = e - oce * 72;
      s_w[e] = w[((size_t)(oc0 + oce) * 2048 + (ic0 + icb)) * 9 + rem];
    }
    __syncthreads();
#pragma unroll
    for (int ic = 0; ic < 8; ic++) {
#pragma unroll
      for (int k = 0; k < 9; k++) {
        const int ko = (k / 3) * 16 + (k % 3);
        float wv0 = s_w[(ocg * 4 + 0) * 72 + ic * 9 + k];
        float wv1 = s_w[(ocg * 4 + 1) * 72 + ic * 9 + k];
        float wv2 = s_w[(ocg * 4 + 2) * 72 + ic * 9 + k];
        float wv3 = s_w[(ocg * 4 + 3) * 72 + ic * 9 + k];
#pragma unroll
        for (int j = 0; j < 7; j++) {
          float iv = s_in[ic * 256 + pofs[j] + ko];
          acc[0][j] += wv0 * iv;
          acc[1][j] += wv1 * iv;
          acc[2][j] += wv2 * iv;
          acc[3][j] += wv3 * iv;
        }
      }
    }
  }
  float* po = part + (((size_t)kc * NB + b) * 128 + oc0) * 196;
#pragma unroll
  for (int i = 0; i < 4; i++)
#pragma unroll
    for (int j = 0; j < 7; j++)
      if (pval[j]) po[(ocg * 4 + i) * 196 + posg + 32 * j] = acc[i][j];
}

__global__ void conv1_finish(const float* __restrict__ part,
                             const float* __restrict__ bias,
                             float* __restrict__ d1) {
  int i = blockIdx.x * 256 + threadIdx.x;
  if (i >= NB * 128 * 196) return;
  int oc = (i / 196) & 127;
  float s = bias[oc];
#pragma unroll
  for (int k = 0; k < 8; k++) s += part[(size_t)k * (NB * 128 * 196) + i];
  d1[i] = fmaxf(s, 0.f);
}

// ---------------- conv2: d1 [16,128,14,14] -> d2 [16,128,7,7], stride2 pad1 ----------------
__global__ __launch_bounds__(256, 2)
void conv2_kernel(const float* __restrict__ d1, const float* __restrict__ w,
                  const float* __restrict__ bias, float* __restrict__ d2) {
  const int bid = blockIdx.x;   // 64 = 16 b x 4 oc-tiles
  const int ot = bid & 3, b = bid >> 2;
  const int oc0 = ot * 32;
  const int tid = threadIdx.x;
  const int ocl = tid >> 3;     // 0..31
  const int posg = tid & 7;     // p = posg + 8j, j<7  (49 valid)

  __shared__ float s_in[16 * 256];
  __shared__ float s_w[32 * 144];

  float acc[7];
#pragma unroll
  for (int j = 0; j < 7; j++) acc[j] = 0.f;
  int pofs[7];
  bool pval[7];
#pragma unroll
  for (int j = 0; j < 7; j++) {
    int p = posg + 8 * j;
    pval[j] = (p < 49);
    int y = pval[j] ? (p / 7) : 0;
    int x = pval[j] ? (p % 7) : 0;
    pofs[j] = 2 * y * 16 + 2 * x;   // + ky*16 + kx
  }

  for (int icb = 0; icb < 128; icb += 16) {
    __syncthreads();
#pragma unroll
    for (int r = 0; r < 16; r++) {
      int e = tid + 256 * r;
      int ch = e >> 8, idx = e & 255;
      int ty = idx >> 4, tx = idx & 15;
      int iy = ty - 1, ix = tx - 1;
      float v = 0.f;
      if ((unsigned)iy < 14u && (unsigned)ix < 14u)
        v = d1[((size_t)b * 128 + icb + ch) * 196 + iy * 14 + ix];
      s_in[e] = v;
    }
#pragma unroll
    for (int r = 0; r < 18; r++) {
      int e = tid + 256 * r;
      int oce = e / 144, rem = e - oce * 144;
      s_w[e] = w[((size_t)(oc0 + oce) * 128 + icb) * 9 + rem];
    }
    __syncthreads();
#pragma unroll
    for (int ic = 0; ic < 16; ic++) {
#pragma unroll
      for (int k = 0; k < 9; k++) {
        float wv = s_w[ocl * 144 + ic * 9 + k];
        int ko = (k / 3) * 16 + (k % 3);
#pragma unroll
        for (int j = 0; j < 7; j++)
          acc[j] += wv * s_in[ic * 256 + pofs[j] + ko];
      }
    }
  }
  float bb = bias[oc0 + ocl];
#pragma unroll
  for (int j = 0; j < 7; j++) {
    int p = posg + 8 * j;
    if (pval[j]) d2[((size_t)b * 128 + oc0 + ocl) * 49 + p] = fmaxf(acc[j] + bb, 0.f);
  }
}

// ---------------- conv3: d2 [16,128,7,7] -> d3 [16,128,4,4], stride2 pad1 ----------------
__global__ __launch_bounds__(256, 2)
void conv3_kernel(const float* __restrict__ d2, const float* __restrict__ w,
                  const float* __restrict__ bias, float* __restrict__ d3) {
  const int bid = blockIdx.x;  // 128 = 16 b x 8 oc-tiles(16)
  const int ot = bid & 7, b = bid >> 3;
  const int oc0 = ot * 16;
  const int tid = threadIdx.x;

  __shared__ float s_in[128 * 81];   // full input, 9x9 padded per ch
  __shared__ float s_w[16 * 288];    // 16 oc x (32 ic x 9)

  for (int e = tid; e < 128 * 81; e += 256) {
    int ch = e / 81, idx = e - ch * 81;
    int ty = idx / 9, tx = idx - ty * 9;
    int iy = ty - 1, ix = tx - 1;
    float v = 0.f;
    if ((unsigned)iy < 7u && (unsigned)ix < 7u)
      v = d2[((size_t)b * 128 + ch) * 49 + iy * 7 + ix];
    s_in[e] = v;
  }

  const int oc = tid >> 4, p = tid & 15;
  const int y = p >> 2, x = p & 3;
  const int base = 2 * y * 9 + 2 * x;
  float acc = 0.f;

  for (int icb = 0; icb < 128; icb += 32) {
    __syncthreads();
#pragma unroll
    for (int r = 0; r < 18; r++) {
      int e = tid + 256 * r;
      int oce = e / 288, rem = e - oce * 288;
      s_w[e] = w[((size_t)(oc0 + oce) * 128 + icb) * 9 + rem];
    }
    __syncthreads();
    for (int ic = 0; ic < 32; ic++) {
#pragma unroll
      for (int k = 0; k < 9; k++)
        acc += s_w[oc * 288 + ic * 9 + k] *
               s_in[(icb + ic) * 81 + base + (k / 3) * 9 + (k % 3)];
    }
  }
  d3[((size_t)b * 128 + oc0 + oc) * 16 + p] = fmaxf(acc + bias[oc0 + oc], 0.f);
}

// ---------------- tidy 1x1 convs -> rpn_score [16,1614] ----------------
__global__ void tidy_kernel(const float* __restrict__ d1, const float* __restrict__ d2,
                            const float* __restrict__ d3,
                            const float* __restrict__ w1, const float* __restrict__ b1,
                            const float* __restrict__ w2, const float* __restrict__ b2,
                            const float* __restrict__ w3, const float* __restrict__ b3,
                            float* __restrict__ score) {
  int i = blockIdx.x * 256 + threadIdx.x;
  if (i >= NB * NA) return;
  int b = i / NA, j = i - b * NA;
  float s;
  if (j < 1176) {
    int oc = j / 196, p = j - oc * 196;
    const float* in = d1 + (size_t)b * 128 * 196 + p;
    const float* w = w1 + oc * 128;
    s = b1[oc];
    for (int ic = 0; ic < 128; ic++) s += in[(size_t)ic * 196] * w[ic];
  } else if (j < 1470) {
    int jj = j - 1176;
    int oc = jj / 49, p = jj - oc * 49;
    const float* in = d2 + (size_t)b * 128 * 49 + p;
    const float* w = w2 + oc * 128;
    s = b2[oc];
    for (int ic = 0; ic < 128; ic++) s += in[(size_t)ic * 49] * w[ic];
  } else {
    int jj = j - 1470;
    int oc = jj / 16, p = jj & 15;
    const float* in = d3 + (size_t)b * 128 * 16 + p;
    const float* w = w3 + oc * 128;
    s = b3[oc];
    for (int ic = 0; ic < 128; ic++) s += in[(size_t)ic * 16] * w[ic];
  }
  score[i] = s;
}

// ---------------- NMS: per batch, TOPN=4, IoU>0.25 suppress ----------------
__global__ void nms_kernel(const float* __restrict__ score, const int* __restrict__ anchors,
                           float* __restrict__ out_idx, float* __restrict__ out_prob,
                           float* __restrict__ sel) {
  __shared__ float s_sc[NA];
  __shared__ float s_bx[NA * 4];
  __shared__ float r_s[256];
  __shared__ int r_i[256];
  const int b = blockIdx.x, tid = threadIdx.x;

  for (int i = tid; i < NA; i += 256) {
    s_sc[i] = score[b * NA + i];
    s_bx[i * 4 + 0] = (float)anchors[i * 4 + 0];
    s_bx[i * 4 + 1] = (float)anchors[i * 4 + 1];
    s_bx[i * 4 + 2] = (float)anchors[i * 4 + 2];
    s_bx[i * 4 + 3] = (float)anchors[i * 4 + 3];
  }
  __syncthreads();

  for (int t = 0; t < 4; t++) {
    float bs = -__builtin_inff();
    int bi = NA;
    for (int i = tid; i < NA; i += 256) {
      float s = s_sc[i];
      if (s > bs || (s == bs && i < bi)) { bs = s; bi = i; }
    }
    r_s[tid] = bs; r_i[tid] = bi;
    __syncthreads();
    for (int off = 128; off > 0; off >>= 1) {
      if (tid < off) {
        float s2 = r_s[tid + off]; int i2 = r_i[tid + off];
        if (s2 > r_s[tid] || (s2 == r_s[tid] && i2 < r_i[tid])) { r_s[tid] = s2; r_i[tid] = i2; }
      }
      __syncthreads();
    }
    const int idx = r_i[0];
    const float by0 = s_bx[idx * 4 + 0], bx0 = s_bx[idx * 4 + 1];
    const float by1 = s_bx[idx * 4 + 2], bx1 = s_bx[idx * 4 + 3];
    if (tid == 0) {
      out_idx[b * 4 + t] = (float)idx;
      out_prob[b * 4 + t] = s_sc[idx];
      sel[(b * 4 + t) * 4 + 0] = by0;
      sel[(b * 4 + t) * 4 + 1] = bx0;
      sel[(b * 4 + t) * 4 + 2] = by1;
      sel[(b * 4 + t) * 4 + 3] = bx1;
    }
    __syncthreads();  // prob read & idx broadcast complete before masking
    const float a = (by1 - by0) * (bx1 - bx0);
    for (int i = tid; i < NA; i += 256) {
      float cy0 = s_bx[i * 4 + 0], cx0 = s_bx[i * 4 + 1];
      float cy1 = s_bx[i * 4 + 2], cx1 = s_bx[i * 4 + 3];
      float yy0 = fmaxf(by0, cy0), xx0 = fmaxf(bx0, cx0);
      float yy1 = fminf(by1, cy1), xx1 = fminf(bx1, cx1);
      float inter = fmaxf(yy1 - yy0, 0.f) * fmaxf(xx1 - xx0, 0.f);
      float ar = (cy1 - cy0) * (cx1 - cx0);
      float iou = inter / (a + ar - inter);
      if (iou > 0.25f) s_sc[i] = -__builtin_inff();
    }
    __syncthreads();
  }
}

// ---------------- crop+bilinear resize to [16,4,3,224,224] ----------------
__global__ void crop_kernel(const float* __restrict__ x, const float* __restrict__ sel,
                            float* __restrict__ out) {
  long long i = (long long)blockIdx.x * 256 + threadIdx.x;
  const long long total = (long long)NB * 4 * 3 * 224 * 224;
  if (i >= total) return;
  int px = (int)(i % 224);
  long long t = i / 224;
  int py = (int)(t % 224); t /= 224;
  int ch = (int)(t % 3);  t /= 3;
  int n  = (int)(t % 4);
  int b  = (int)(t / 4);

  const float* bx = sel + (b * 4 + n) * 4;
  const float y0 = bx[0], x0 = bx[1], y1 = bx[2], x1 = bx[3];

  float ty = (float)py / 223.0f;
  float cy = y0 + (y1 - 1.0f - y0) * ty;
  float cyf = floorf(cy);
  int ylo = (int)cyf; ylo = ylo < 0 ? 0 : (ylo > 895 ? 895 : ylo);
  int yhi = ylo + 1 > 895 ? 895 : ylo + 1;
  float wy = cy - cyf;

  float tx = (float)px / 223.0f;
  float cx = x0 + (x1 - 1.0f - x0) * tx;
  float cxf = floorf(cx);
  int xlo = (int)cxf; xlo = xlo < 0 ? 0 : (xlo > 895 ? 895 : xlo);
  int xhi = xlo + 1 > 895 ? 895 : xlo + 1;
  float wx = cx - cxf;

  const float* img = x + ((size_t)b * 3 + ch) * 448 * 448;
  auto g = [&](int yy, int xx) -> float {
    yy -= 224; xx -= 224;
    if ((unsigned)yy < 448u && (unsigned)xx < 448u)
      return img[(size_t)yy * 448 + xx];
    return 0.f;
  };
  float v00 = g(ylo, xlo), v01 = g(ylo, xhi);
  float v10 = g(yhi, xlo), v11 = g(yhi, xhi);
  float r = (1.f - wy) * ((1.f - wx) * v00 + wx * v01) +
            wy * ((1.f - wx) * v10 + wx * v11);
  out[i] = r;
}

extern "C" void kernel_launch(void* const* d_in, const int* in_sizes, int n_in,
                              void* d_out, int out_size, void* d_ws, size_t ws_size,
                              hipStream_t stream) {
  const float* x    = (const float*)d_in[0];
  const float* rpn  = (const float*)d_in[1];
  const int*   anc  = (const int*)d_in[2];
  const float* w_d1 = (const float*)d_in[3];
  const float* b_d1 = (const float*)d_in[4];
  const float* w_d2 = (const float*)d_in[5];
  const float* b_d2 = (const float*)d_in[6];
  const float* w_d3 = (const float*)d_in[7];
  const float* b_d3 = (const float*)d_in[8];
  const float* w_t1 = (const float*)d_in[9];
  const float* b_t1 = (const float*)d_in[10];
  const float* w_t2 = (const float*)d_in[11];
  const float* b_t2 = (const float*)d_in[12];
  const float* w_t3 = (const float*)d_in[13];
  const float* b_t3 = (const float*)d_in[14];

  float* out = (float*)d_out;
  float* ws = (float*)d_ws;

  float* part = ws;                       // 8*16*128*196 = 3,211,264
  float* d1   = part + 3211264;           // 401,408
  float* d2   = d1 + 401408;              // 100,352
  float* d3   = d2 + 100352;              // 32,768
  float* sel  = d3 + 32768;               // 256

  float* score    = out;                  // 25824
  float* out_idx  = out + 25824;          // 64
  float* out_prob = out + 25888;          // 64
  float* parts    = out + 25952;          // 9,633,792

  conv1_part<<<dim3(512), dim3(256), 0, stream>>>(rpn, w_d1, part);
  conv1_finish<<<dim3(1568), dim3(256), 0, stream>>>(part, b_d1, d1);
  conv2_kernel<<<dim3(64), dim3(256), 0, stream>>>(d1, w_d2, b_d2, d2);
  conv3_kernel<<<dim3(128), dim3(256), 0, stream>>>(d2, w_d3, b_d3, d3);
  tidy_kernel<<<dim3(101), dim3(256), 0, stream>>>(d1, d2, d3, w_t1, b_t1, w_t2, b_t2,
                                                   w_t3, b_t3, score);
  nms_kernel<<<dim3(16), dim3(256), 0, stream>>>(score, anc, out_idx, out_prob, sel);
  crop_kernel<<<dim3(37632), dim3(256), 0, stream>>>(x, sel, parts);
}

// Round 2
// 564.420 us; speedup vs baseline: 1.1217x; 1.1217x over previous
//
#include <hip/hip_runtime.h>
#include <hip/hip_bf16.h>

#define NB 16
#define NA 1614

// ---------------- conv1: rpn_feature [16,2048,14,14] * w[128,2048,3,3] pad1 ----------------
// split-K: grid 512 = 8 kc x 4 oct x 16 b. Block: 32 oc x 224 pos-slots (16 rows x 14), K=256 ic.
// Thread: 4 oc x 7 contiguous cols. tid = posg*8 + ocg; posg: xh = posg>>4 (wave-uniform), y = posg&15.

template<int XOFF>
__device__ __forceinline__ void conv1_inner(const float* __restrict__ si,
                                            const float* __restrict__ swp,
                                            float acc[4][7]) {
#pragma unroll
  for (int ky = 0; ky < 3; ky++) {
    const float4 a = *(const float4*)(si + ky * 16);
    const float4 b = *(const float4*)(si + ky * 16 + 4);
    const float4 c = *(const float4*)(si + ky * 16 + 8);
    const float iv[12] = {a.x, a.y, a.z, a.w, b.x, b.y, b.z, b.w, c.x, c.y, c.z, c.w};
#pragma unroll
    for (int kx = 0; kx < 3; kx++) {
      const float4 wv = *(const float4*)(swp + (ky * 3 + kx) * 36);
#pragma unroll
      for (int x = 0; x < 7; x++) {
        const float v = iv[XOFF + x + kx];
        acc[0][x] = fmaf(wv.x, v, acc[0][x]);
        acc[1][x] = fmaf(wv.y, v, acc[1][x]);
        acc[2][x] = fmaf(wv.z, v, acc[2][x]);
        acc[3][x] = fmaf(wv.w, v, acc[3][x]);
      }
    }
  }
}

__global__ __launch_bounds__(256, 2)
void conv1_part(const float* __restrict__ in, const float* __restrict__ w,
                float* __restrict__ part) {
  const int bid = blockIdx.x;
  const int kc  = bid & 7;
  const int oct = (bid >> 3) & 3;
  const int b   = bid >> 5;
  const int ic0 = kc * 256;
  const int oc0 = oct * 32;
  const int tid = threadIdx.x;
  const int ocg  = tid & 7;        // oc = oc0 + ocg*4 + {0..3}
  const int posg = tid >> 3;       // 0..31
  const int xh   = posg >> 4;      // wave-uniform (waves 0,1 -> 0; waves 2,3 -> 1)
  const int y    = posg & 15;      // rows 0..15 (14,15 are pad, discarded)

  __shared__ float s_in[16 * 288];   // [ch][row18][col16], tile col t = input col t-1
  __shared__ float s_w[16 * 324];    // [ch][tap*36 + oc32]

  float acc[4][7] = {};

  const float* inb = in + (size_t)b * 2048 * 196;
  const int ivb = y * 16 + xh * 4;   // float offset of first b128 within channel

  for (int icb = 0; icb < 256; icb += 16) {
    __syncthreads();
    // stage input: 16 ch x 18 rows x 16 cols, zero-padded
#pragma unroll
    for (int r = 0; r < 18; r++) {
      const int e = tid + 256 * r;               // 0..4607
      const int ch = e / 288, idx = e - ch * 288;
      const int tr = idx >> 4, tc = idx & 15;
      const int iy = tr - 1, ix = tc - 1;
      float v = 0.f;
      if ((unsigned)iy < 14u && (unsigned)ix < 14u)
        v = inb[(size_t)(ic0 + icb + ch) * 196 + iy * 14 + ix];
      s_in[e] = v;
    }
    // stage weights transposed: global runs of 144 contiguous floats per oc
#pragma unroll
    for (int r = 0; r < 18; r++) {
      const int e = tid + 256 * r;               // 0..4607
      const int oc = e / 144, rem = e - oc * 144;
      const int ch = rem / 9, tap = rem - ch * 9;
      const float v = w[(size_t)(oc0 + oc) * 18432 + (size_t)(ic0 + icb) * 9 + rem];
      s_w[ch * 324 + tap * 36 + oc] = v;
    }
    __syncthreads();

    if (xh == 0) {
      for (int ic = 0; ic < 16; ic++)
        conv1_inner<0>(s_in + ic * 288 + ivb, s_w + ic * 324 + ocg * 4, acc);
    } else {
      for (int ic = 0; ic < 16; ic++)
        conv1_inner<3>(s_in + ic * 288 + ivb, s_w + ic * 324 + ocg * 4, acc);
    }
  }

  if (y < 14) {
    float* po = part + (((size_t)kc * NB + b) * 128 + oc0 + ocg * 4) * 196 + y * 14 + xh * 7;
#pragma unroll
    for (int i = 0; i < 4; i++)
#pragma unroll
      for (int x = 0; x < 7; x++)
        po[(size_t)i * 196 + x] = acc[i][x];
  }
}

__global__ void conv1_finish(const float* __restrict__ part,
                             const float* __restrict__ bias,
                             float* __restrict__ d1) {
  const int i4 = blockIdx.x * 256 + threadIdx.x;
  if (i4 >= NB * 128 * 49) return;          // 100352 float4 groups
  const int i = i4 * 4;
  const int oc = (i / 196) & 127;
  const float bb = bias[oc];                 // 196 % 4 == 0 -> all 4 share oc
  float4 s = {bb, bb, bb, bb};
#pragma unroll
  for (int k = 0; k < 8; k++) {
    const float4 p = *(const float4*)(part + (size_t)k * (NB * 128 * 196) + i);
    s.x += p.x; s.y += p.y; s.z += p.z; s.w += p.w;
  }
  s.x = fmaxf(s.x, 0.f); s.y = fmaxf(s.y, 0.f);
  s.z = fmaxf(s.z, 0.f); s.w = fmaxf(s.w, 0.f);
  *(float4*)(d1 + i) = s;
}

// ---------------- conv2: d1 [16,128,14,14] -> d2 [16,128,7,7], stride2 pad1 ----------------
__global__ __launch_bounds__(256, 2)
void conv2_kernel(const float* __restrict__ d1, const float* __restrict__ w,
                  const float* __restrict__ bias, float* __restrict__ d2) {
  const int bid = blockIdx.x;   // 64 = 16 b x 4 oc-tiles
  const int ot = bid & 3, b = bid >> 2;
  const int oc0 = ot * 32;
  const int tid = threadIdx.x;
  const int ocl = tid >> 3;     // 0..31
  const int posg = tid & 7;     // p = posg + 8j, j<7  (49 valid)

  __shared__ float s_in[16 * 256];
  __shared__ float s_w[32 * 144];

  float acc[7];
#pragma unroll
  for (int j = 0; j < 7; j++) acc[j] = 0.f;
  int pofs[7];
  bool pval[7];
#pragma unroll
  for (int j = 0; j < 7; j++) {
    int p = posg + 8 * j;
    pval[j] = (p < 49);
    int y = pval[j] ? (p / 7) : 0;
    int x = pval[j] ? (p % 7) : 0;
    pofs[j] = 2 * y * 16 + 2 * x;   // + ky*16 + kx
  }

  for (int icb = 0; icb < 128; icb += 16) {
    __syncthreads();
#pragma unroll
    for (int r = 0; r < 16; r++) {
      int e = tid + 256 * r;
      int ch = e >> 8, idx = e & 255;
      int ty = idx >> 4, tx = idx & 15;
      int iy = ty - 1, ix = tx - 1;
      float v = 0.f;
      if ((unsigned)iy < 14u && (unsigned)ix < 14u)
        v = d1[((size_t)b * 128 + icb + ch) * 196 + iy * 14 + ix];
      s_in[e] = v;
    }
#pragma unroll
    for (int r = 0; r < 18; r++) {
      int e = tid + 256 * r;
      int oce = e / 144, rem = e - oce * 144;
      s_w[e] = w[((size_t)(oc0 + oce) * 128 + icb) * 9 + rem];
    }
    __syncthreads();
#pragma unroll
    for (int ic = 0; ic < 16; ic++) {
#pragma unroll
      for (int k = 0; k < 9; k++) {
        float wv = s_w[ocl * 144 + ic * 9 + k];
        int ko = (k / 3) * 16 + (k % 3);
#pragma unroll
        for (int j = 0; j < 7; j++)
          acc[j] += wv * s_in[ic * 256 + pofs[j] + ko];
      }
    }
  }
  float bb = bias[oc0 + ocl];
#pragma unroll
  for (int j = 0; j < 7; j++) {
    int p = posg + 8 * j;
    if (pval[j]) d2[((size_t)b * 128 + oc0 + ocl) * 49 + p] = fmaxf(acc[j] + bb, 0.f);
  }
}

// ---------------- conv3: d2 [16,128,7,7] -> d3 [16,128,4,4], stride2 pad1 ----------------
__global__ __launch_bounds__(256, 2)
void conv3_kernel(const float* __restrict__ d2, const float* __restrict__ w,
                  const float* __restrict__ bias, float* __restrict__ d3) {
  const int bid = blockIdx.x;  // 128 = 16 b x 8 oc-tiles(16)
  const int ot = bid & 7, b = bid >> 3;
  const int oc0 = ot * 16;
  const int tid = threadIdx.x;

  __shared__ float s_in[128 * 81];   // full input, 9x9 padded per ch
  __shared__ float s_w[16 * 288];    // 16 oc x (32 ic x 9)

  for (int e = tid; e < 128 * 81; e += 256) {
    int ch = e / 81, idx = e - ch * 81;
    int ty = idx / 9, tx = idx - ty * 9;
    int iy = ty - 1, ix = tx - 1;
    float v = 0.f;
    if ((unsigned)iy < 7u && (unsigned)ix < 7u)
      v = d2[((size_t)b * 128 + ch) * 49 + iy * 7 + ix];
    s_in[e] = v;
  }

  const int oc = tid >> 4, p = tid & 15;
  const int y = p >> 2, x = p & 3;
  const int base = 2 * y * 9 + 2 * x;
  float acc = 0.f;

  for (int icb = 0; icb < 128; icb += 32) {
    __syncthreads();
#pragma unroll
    for (int r = 0; r < 18; r++) {
      int e = tid + 256 * r;
      int oce = e / 288, rem = e - oce * 288;
      s_w[e] = w[((size_t)(oc0 + oce) * 128 + icb) * 9 + rem];
    }
    __syncthreads();
    for (int ic = 0; ic < 32; ic++) {
#pragma unroll
      for (int k = 0; k < 9; k++)
        acc += s_w[oc * 288 + ic * 9 + k] *
               s_in[(icb + ic) * 81 + base + (k / 3) * 9 + (k % 3)];
    }
  }
  d3[((size_t)b * 128 + oc0 + oc) * 16 + p] = fmaxf(acc + bias[oc0 + oc], 0.f);
}

// ---------------- tidy 1x1 convs -> rpn_score [16,1614] ----------------
__global__ void tidy_kernel(const float* __restrict__ d1, const float* __restrict__ d2,
                            const float* __restrict__ d3,
                            const float* __restrict__ w1, const float* __restrict__ b1,
                            const float* __restrict__ w2, const float* __restrict__ b2,
                            const float* __restrict__ w3, const float* __restrict__ b3,
                            float* __restrict__ score) {
  int i = blockIdx.x * 256 + threadIdx.x;
  if (i >= NB * NA) return;
  int b = i / NA, j = i - b * NA;
  float s;
  if (j < 1176) {
    int oc = j / 196, p = j - oc * 196;
    const float* in = d1 + (size_t)b * 128 * 196 + p;
    const float* w = w1 + oc * 128;
    s = b1[oc];
    for (int ic = 0; ic < 128; ic++) s += in[(size_t)ic * 196] * w[ic];
  } else if (j < 1470) {
    int jj = j - 1176;
    int oc = jj / 49, p = jj - oc * 49;
    const float* in = d2 + (size_t)b * 128 * 49 + p;
    const float* w = w2 + oc * 128;
    s = b2[oc];
    for (int ic = 0; ic < 128; ic++) s += in[(size_t)ic * 49] * w[ic];
  } else {
    int jj = j - 1470;
    int oc = jj / 16, p = jj & 15;
    const float* in = d3 + (size_t)b * 128 * 16 + p;
    const float* w = w3 + oc * 128;
    s = b3[oc];
    for (int ic = 0; ic < 128; ic++) s += in[(size_t)ic * 16] * w[ic];
  }
  score[i] = s;
}

// ---------------- NMS: per batch, TOPN=4, IoU>0.25 suppress ----------------
__global__ void nms_kernel(const float* __restrict__ score, const int* __restrict__ anchors,
                           float* __restrict__ out_idx, float* __restrict__ out_prob,
                           float* __restrict__ sel) {
  __shared__ float s_sc[NA];
  __shared__ float s_bx[NA * 4];
  __shared__ float r_s[256];
  __shared__ int r_i[256];
  const int b = blockIdx.x, tid = threadIdx.x;

  for (int i = tid; i < NA; i += 256) {
    s_sc[i] = score[b * NA + i];
    s_bx[i * 4 + 0] = (float)anchors[i * 4 + 0];
    s_bx[i * 4 + 1] = (float)anchors[i * 4 + 1];
    s_bx[i * 4 + 2] = (float)anchors[i * 4 + 2];
    s_bx[i * 4 + 3] = (float)anchors[i * 4 + 3];
  }
  __syncthreads();

  for (int t = 0; t < 4; t++) {
    float bs = -__builtin_inff();
    int bi = NA;
    for (int i = tid; i < NA; i += 256) {
      float s = s_sc[i];
      if (s > bs || (s == bs && i < bi)) { bs = s; bi = i; }
    }
    r_s[tid] = bs; r_i[tid] = bi;
    __syncthreads();
    for (int off = 128; off > 0; off >>= 1) {
      if (tid < off) {
        float s2 = r_s[tid + off]; int i2 = r_i[tid + off];
        if (s2 > r_s[tid] || (s2 == r_s[tid] && i2 < r_i[tid])) { r_s[tid] = s2; r_i[tid] = i2; }
      }
      __syncthreads();
    }
    const int idx = r_i[0];
    const float by0 = s_bx[idx * 4 + 0], bx0 = s_bx[idx * 4 + 1];
    const float by1 = s_bx[idx * 4 + 2], bx1 = s_bx[idx * 4 + 3];
    if (tid == 0) {
      out_idx[b * 4 + t] = (float)idx;
      out_prob[b * 4 + t] = s_sc[idx];
      sel[(b * 4 + t) * 4 + 0] = by0;
      sel[(b * 4 + t) * 4 + 1] = bx0;
      sel[(b * 4 + t) * 4 + 2] = by1;
      sel[(b * 4 + t) * 4 + 3] = bx1;
    }
    __syncthreads();  // prob read & idx broadcast complete before masking
    const float a = (by1 - by0) * (bx1 - bx0);
    for (int i = tid; i < NA; i += 256) {
      float cy0 = s_bx[i * 4 + 0], cx0 = s_bx[i * 4 + 1];
      float cy1 = s_bx[i * 4 + 2], cx1 = s_bx[i * 4 + 3];
      float yy0 = fmaxf(by0, cy0), xx0 = fmaxf(bx0, cx0);
      float yy1 = fminf(by1, cy1), xx1 = fminf(bx1, cx1);
      float inter = fmaxf(yy1 - yy0, 0.f) * fmaxf(xx1 - xx0, 0.f);
      float ar = (cy1 - cy0) * (cx1 - cx0);
      float iou = inter / (a + ar - inter);
      if (iou > 0.25f) s_sc[i] = -__builtin_inff();
    }
    __syncthreads();
  }
}

// ---------------- crop+bilinear resize to [16,4,3,224,224] ----------------
__global__ void crop_kernel(const float* __restrict__ x, const float* __restrict__ sel,
                            float* __restrict__ out) {
  long long i = (long long)blockIdx.x * 256 + threadIdx.x;
  const long long total = (long long)NB * 4 * 3 * 224 * 224;
  if (i >= total) return;
  int px = (int)(i % 224);
  long long t = i / 224;
  int py = (int)(t % 224); t /= 224;
  int ch = (int)(t % 3);  t /= 3;
  int n  = (int)(t % 4);
  int b  = (int)(t / 4);

  const float* bx = sel + (b * 4 + n) * 4;
  const float y0 = bx[0], x0 = bx[1], y1 = bx[2], x1 = bx[3];

  float ty = (float)py / 223.0f;
  float cy = y0 + (y1 - 1.0f - y0) * ty;
  float cyf = floorf(cy);
  int ylo = (int)cyf; ylo = ylo < 0 ? 0 : (ylo > 895 ? 895 : ylo);
  int yhi = ylo + 1 > 895 ? 895 : ylo + 1;
  float wy = cy - cyf;

  float tx = (float)px / 223.0f;
  float cx = x0 + (x1 - 1.0f - x0) * tx;
  float cxf = floorf(cx);
  int xlo = (int)cxf; xlo = xlo < 0 ? 0 : (xlo > 895 ? 895 : xlo);
  int xhi = xlo + 1 > 895 ? 895 : xlo + 1;
  float wx = cx - cxf;

  const float* img = x + ((size_t)b * 3 + ch) * 448 * 448;
  auto g = [&](int yy, int xx) -> float {
    yy -= 224; xx -= 224;
    if ((unsigned)yy < 448u && (unsigned)xx < 448u)
      return img[(size_t)yy * 448 + xx];
    return 0.f;
  };
  float v00 = g(ylo, xlo), v01 = g(ylo, xhi);
  float v10 = g(yhi, xlo), v11 = g(yhi, xhi);
  float r = (1.f - wy) * ((1.f - wx) * v00 + wx * v01) +
            wy * ((1.f - wx) * v10 + wx * v11);
  out[i] = r;
}

extern "C" void kernel_launch(void* const* d_in, const int* in_sizes, int n_in,
                              void* d_out, int out_size, void* d_ws, size_t ws_size,
                              hipStream_t stream) {
  const float* x    = (const float*)d_in[0];
  const float* rpn  = (const float*)d_in[1];
  const int*   anc  = (const int*)d_in[2];
  const float* w_d1 = (const float*)d_in[3];
  const float* b_d1 = (const float*)d_in[4];
  const float* w_d2 = (const float*)d_in[5];
  const float* b_d2 = (const float*)d_in[6];
  const float* w_d3 = (const float*)d_in[7];
  const float* b_d3 = (const float*)d_in[8];
  const float* w_t1 = (const float*)d_in[9];
  const float* b_t1 = (const float*)d_in[10];
  const float* w_t2 = (const float*)d_in[11];
  const float* b_t2 = (const float*)d_in[12];
  const float* w_t3 = (const float*)d_in[13];
  const float* b_t3 = (const float*)d_in[14];

  float* out = (float*)d_out;
  float* ws = (float*)d_ws;

  float* part = ws;                       // 8*16*128*196 = 3,211,264
  float* d1   = part + 3211264;           // 401,408
  float* d2   = d1 + 401408;              // 100,352
  float* d3   = d2 + 100352;              // 32,768
  float* sel  = d3 + 32768;               // 256

  float* score    = out;                  // 25824
  float* out_idx  = out + 25824;          // 64
  float* out_prob = out + 25888;          // 64
  float* parts    = out + 25952;          // 9,633,792

  conv1_part<<<dim3(512), dim3(256), 0, stream>>>(rpn, w_d1, part);
  conv1_finish<<<dim3(392), dim3(256), 0, stream>>>(part, b_d1, d1);
  conv2_kernel<<<dim3(64), dim3(256), 0, stream>>>(d1, w_d2, b_d2, d2);
  conv3_kernel<<<dim3(128), dim3(256), 0, stream>>>(d2, w_d3, b_d3, d3);
  tidy_kernel<<<dim3(101), dim3(256), 0, stream>>>(d1, d2, d3, w_t1, b_t1, w_t2, b_t2,
                                                   w_t3, b_t3, score);
  nms_kernel<<<dim3(16), dim3(256), 0, stream>>>(score, anc, out_idx, out_prob, sel);
  crop_kernel<<<dim3(37632), dim3(256), 0, stream>>>(x, sel, parts);
}